// Round 1
// baseline (1463.490 us; speedup 1.0000x reference)
//
#include <hip/hip_runtime.h>

#define NUM_CODES 4096
#define CODE_DIM  64
#define NPTS      65536          // B*S = 16*4096
#define NSEG      4
#define SEG_CODES (NUM_CODES / NSEG)   // 1024
#define DECAYF    0.99f
#define EPSF      1e-5f

// ---------------- workspace layout (float indices) ----------------
// [0, 4096)                  batch_cluster accumulator
// [4096, 4096+262144)        embed_sum accumulator
// [266240]                   n accumulator (scalar)
// [266244, 266244+4096)      csq (codebook squared norms)
// [270340, +65536*4*4)       top2 per (point, segment) as float4 {m1, i1, m2, i2}
#define WS_BC   0
#define WS_ES   4096
#define WS_N    266240
#define WS_CSQ  266244
#define WS_TOP2 270340

// ---------------- output layout (floats, concatenated) ----------------
// quantized [4194304] | indices [65536] | new_codebook [262144] |
// new_cluster_size [4096] | new_ema_w [262144]
#define OUT_Q    0
#define OUT_IDX  4194304
#define OUT_CB   4259840
#define OUT_CS   4521984
#define OUT_EMA  4526080

__global__ __launch_bounds__(256) void csq_kernel(const float* __restrict__ cb,
                                                  float* __restrict__ csq) {
    int k = blockIdx.x * 256 + threadIdx.x;   // 4096 threads
    const float4* cp = (const float4*)(cb + (size_t)k * CODE_DIM);
    float s0 = 0.f, s1 = 0.f, s2 = 0.f, s3 = 0.f;
#pragma unroll
    for (int j = 0; j < 16; ++j) {
        float4 v = cp[j];
        s0 = fmaf(v.x, v.x, s0);
        s1 = fmaf(v.y, v.y, s1);
        s2 = fmaf(v.z, v.z, s2);
        s3 = fmaf(v.w, v.w, s3);
    }
    csq[k] = (s0 + s1) + (s2 + s3);
}

// Each block: 256 points x one code-segment (1024 codes). Codebook reads are
// wave-uniform -> scalar loads (SMEM) feeding v_fma with SGPR operands.
__global__ __launch_bounds__(256) void scan_kernel(const float* __restrict__ x,
                                                   const float* __restrict__ cb,
                                                   const float* __restrict__ csq,
                                                   float4* __restrict__ top2) {
    const int tid  = threadIdx.x;
    const int blk  = blockIdx.x;          // 0..1023
    const int seg  = blk & (NSEG - 1);
    const int pblk = blk >> 2;
    const int p    = pblk * 256 + tid;

    float4 xv[16];
    const float4* xp = (const float4*)(x + (size_t)p * CODE_DIM);
#pragma unroll
    for (int j = 0; j < 16; ++j) xv[j] = xp[j];

    float m1 = 1e30f, m2 = 1e30f;
    int   i1 = 0,     i2 = 0;
    const int c0 = seg * SEG_CODES;

    for (int c = c0; c < c0 + SEG_CODES; ++c) {
        const float4* cp = (const float4*)(cb + (size_t)c * CODE_DIM);
        float d0 = 0.f, d1 = 0.f, d2 = 0.f, d3 = 0.f;
#pragma unroll
        for (int j = 0; j < 16; ++j) {
            float4 cv = cp[j];
            d0 = fmaf(xv[j].x, cv.x, d0);
            d1 = fmaf(xv[j].y, cv.y, d1);
            d2 = fmaf(xv[j].z, cv.z, d2);
            d3 = fmaf(xv[j].w, cv.w, d3);
        }
        float dot  = (d0 + d1) + (d2 + d3);
        float dval = fmaf(-2.0f, dot, csq[c]);   // x_sq is constant per point: drop it
        if (dval < m1)      { m2 = m1; i2 = i1; m1 = dval; i1 = c; }
        else if (dval < m2) { m2 = dval; i2 = c; }
    }
    top2[(size_t)p * NSEG + seg] =
        make_float4(m1, __int_as_float(i1), m2, __int_as_float(i2));
}

// Merge per-segment top2, refine the final decision in f64 (exact vs np ref),
// then emit quantized row + index and scatter the EMA accumulators.
__global__ __launch_bounds__(256) void emit_kernel(const float* __restrict__ x,
                                                   const float* __restrict__ cb,
                                                   const float4* __restrict__ top2,
                                                   float* __restrict__ q_out,
                                                   float* __restrict__ idx_out,
                                                   float* __restrict__ bc_acc,
                                                   float* __restrict__ es_acc) {
    const int p = blockIdx.x * 256 + threadIdx.x;

    float m1 = 1e30f, m2 = 1e30f;
    int   i1 = 0,     i2 = 0;
#pragma unroll
    for (int s = 0; s < NSEG; ++s) {
        float4 t = top2[(size_t)p * NSEG + s];
        float v = t.x; int i = __float_as_int(t.y);
        if (v < m1)      { m2 = m1; i2 = i1; m1 = v; i1 = i; }
        else if (v < m2) { m2 = v; i2 = i; }
        v = t.z; i = __float_as_int(t.w);
        if (v < m1)      { m2 = m1; i2 = i1; m1 = v; i1 = i; }
        else if (v < m2) { m2 = v; i2 = i; }
    }

    const float* xr = x  + (size_t)p  * CODE_DIM;
    const float* c1 = cb + (size_t)i1 * CODE_DIM;
    const float* c2 = cb + (size_t)i2 * CODE_DIM;
    double dot1 = 0.0, q1 = 0.0, dot2 = 0.0, q2 = 0.0;
#pragma unroll 8
    for (int d = 0; d < CODE_DIM; ++d) {
        double xv = (double)xr[d];
        double a  = (double)c1[d];
        double b  = (double)c2[d];
        dot1 += a * xv; q1 += a * a;
        dot2 += b * xv; q2 += b * b;
    }
    double e1 = q1 - 2.0 * dot1;
    double e2 = q2 - 2.0 * dot2;
    int fin;
    if (e1 < e2)      fin = i1;
    else if (e2 < e1) fin = i2;
    else              fin = (i1 < i2) ? i1 : i2;   // exact tie: first index wins

    const float4* cf = (const float4*)(cb + (size_t)fin * CODE_DIM);
    float4* qo = (float4*)(q_out + (size_t)p * CODE_DIM);
#pragma unroll
    for (int j = 0; j < 16; ++j) qo[j] = cf[j];
    idx_out[p] = (float)fin;

    atomicAdd(&bc_acc[fin], 1.0f);
    float* es = es_acc + (size_t)fin * CODE_DIM;
#pragma unroll
    for (int d = 0; d < CODE_DIM; ++d) atomicAdd(&es[d], xr[d]);
}

__global__ __launch_bounds__(256) void ncs_kernel(const float* __restrict__ cs_in,
                                                  const float* __restrict__ bc_acc,
                                                  float* __restrict__ cs_out,
                                                  float* __restrict__ n_acc) {
    int k = blockIdx.x * 256 + threadIdx.x;   // 4096 threads
    float v = DECAYF * cs_in[k] + (1.0f - DECAYF) * bc_acc[k];
    cs_out[k] = v;
    float s = v;
#pragma unroll
    for (int off = 32; off > 0; off >>= 1) s += __shfl_down(s, off);
    if ((threadIdx.x & 63) == 0) atomicAdd(n_acc, s);
}

__global__ __launch_bounds__(256) void finalize_kernel(const float* __restrict__ ema_in,
                                                       const float* __restrict__ es_acc,
                                                       const float* __restrict__ cs_out,
                                                       const float* __restrict__ n_acc,
                                                       float* __restrict__ ema_out,
                                                       float* __restrict__ cb_out) {
    int idx = blockIdx.x * 256 + threadIdx.x;   // 262144 threads
    int k   = idx >> 6;
    float n = *n_acc;
    float ncs = cs_out[k];
    float smoothed = (ncs + EPSF) / (n + (float)NUM_CODES * EPSF) * n;
    float ew = DECAYF * ema_in[idx] + (1.0f - DECAYF) * es_acc[idx];
    ema_out[idx] = ew;
    cb_out[idx]  = ew / smoothed;
}

extern "C" void kernel_launch(void* const* d_in, const int* in_sizes, int n_in,
                              void* d_out, int out_size, void* d_ws, size_t ws_size,
                              hipStream_t stream) {
    const float* x    = (const float*)d_in[0];
    const float* cb   = (const float*)d_in[1];
    const float* cs   = (const float*)d_in[2];
    const float* emaw = (const float*)d_in[3];
    float* out = (float*)d_out;
    float* ws  = (float*)d_ws;

    // zero accumulators (batch_cluster + embed_sum + n)
    hipMemsetAsync(ws, 0, (size_t)(WS_N + 1) * sizeof(float), stream);

    csq_kernel<<<NUM_CODES / 256, 256, 0, stream>>>(cb, ws + WS_CSQ);

    scan_kernel<<<(NPTS / 256) * NSEG, 256, 0, stream>>>(
        x, cb, ws + WS_CSQ, (float4*)(ws + WS_TOP2));

    emit_kernel<<<NPTS / 256, 256, 0, stream>>>(
        x, cb, (const float4*)(ws + WS_TOP2),
        out + OUT_Q, out + OUT_IDX, ws + WS_BC, ws + WS_ES);

    ncs_kernel<<<NUM_CODES / 256, 256, 0, stream>>>(
        cs, ws + WS_BC, out + OUT_CS, ws + WS_N);

    finalize_kernel<<<(NUM_CODES * CODE_DIM) / 256, 256, 0, stream>>>(
        emaw, ws + WS_ES, out + OUT_CS, ws + WS_N, out + OUT_EMA, out + OUT_CB);
}

// Round 2
// 567.990 us; speedup vs baseline: 2.5766x; 2.5766x over previous
//
#include <hip/hip_runtime.h>

#define NUM_CODES 4096
#define CODE_DIM  64
#define NPTS      65536          // B*S = 16*4096
#define NTILES    (NUM_CODES / 16)   // 256 code tiles
#define DECAYF    0.99f
#define EPSF      1e-5f

typedef __attribute__((ext_vector_type(8))) short short8v;
typedef __attribute__((ext_vector_type(4))) float f32x4;
#define MFMA16 __builtin_amdgcn_mfma_f32_16x16x32_bf16

// ---------------- workspace layout (float indices) ----------------
#define WS_BC   0                      // 4096   batch_cluster acc
#define WS_ES   4096                   // 262144 embed_sum acc
#define WS_N    266240                 // 1      n acc
#define WS_CSQ  266244                 // 4096   codebook sq-norms (16B-aligned)
#define WS_CF   270340                 // 262144 floats = 524288 shorts, A-frag codebook
#define WS_TOP2 532484                 // 65536*4 top2 {m1,i1,m2,i2}

// ---------------- output layout ----------------
#define OUT_Q    0
#define OUT_IDX  4194304
#define OUT_CB   4259840
#define OUT_CS   4521984
#define OUT_EMA  4526080

__device__ __forceinline__ unsigned short f2bf(float f) {
    unsigned u = __float_as_uint(f);
    u += 0x7FFFu + ((u >> 16) & 1u);
    return (unsigned short)(u >> 16);
}
__device__ __forceinline__ float bf2f(unsigned short h) {
    return __uint_as_float(((unsigned)h) << 16);
}

// ---------- codebook squared norms ----------
__global__ __launch_bounds__(256) void csq_kernel(const float* __restrict__ cb,
                                                  float* __restrict__ csq) {
    int k = blockIdx.x * 256 + threadIdx.x;   // 4096 threads
    const float4* cp = (const float4*)(cb + (size_t)k * CODE_DIM);
    float s0 = 0.f, s1 = 0.f, s2 = 0.f, s3 = 0.f;
#pragma unroll
    for (int j = 0; j < 16; ++j) {
        float4 v = cp[j];
        s0 = fmaf(v.x, v.x, s0);
        s1 = fmaf(v.y, v.y, s1);
        s2 = fmaf(v.z, v.z, s2);
        s3 = fmaf(v.w, v.w, s3);
    }
    csq[k] = (s0 + s1) + (s2 + s3);
}

// ---------- codebook -> bf16 hi/lo A-fragment layout ----------
// cf[ctile][frag][lane][8 shorts], frag: 0=hi k0, 1=hi k1, 2=lo k0, 3=lo k1.
// A-frag layout (16x16x32): lane holds A[row=lane&15][k=(lane>>4)*8 + j].
__global__ __launch_bounds__(256) void prep_cf(const float* __restrict__ cb,
                                               short* __restrict__ cf) {
    int t = blockIdx.x * 256 + threadIdx.x;   // 32768 threads
    int ctile = t >> 7;
    int rem   = t & 127;
    int khalf = rem >> 6;
    int lane  = rem & 63;
    int code  = ctile * 16 + (lane & 15);
    int kbase = khalf * 32 + (lane >> 4) * 8;
    const float* src = cb + (size_t)code * CODE_DIM + kbase;
    short hi[8], lo[8];
#pragma unroll
    for (int j = 0; j < 8; ++j) {
        float s = -2.0f * src[j];
        unsigned short h = f2bf(s);
        hi[j] = (short)h;
        lo[j] = (short)f2bf(s - bf2f(h));
    }
    short8v H, L;
#pragma unroll
    for (int j = 0; j < 8; ++j) { H[j] = hi[j]; L[j] = lo[j]; }
    *(short8v*)(cf + ((size_t)(ctile * 4 + khalf) * 64 + lane) * 8)     = H;
    *(short8v*)(cf + ((size_t)(ctile * 4 + 2 + khalf) * 64 + lane) * 8) = L;
}

// ---------- per-element top-2 update ----------
#define UPD(v, c, M1, I1, M2, I2) do{ \
    if ((v) < (M1)) { M2 = M1; I2 = I1; M1 = (v); I1 = (c); } \
    else if ((v) < (M2)) { M2 = (v); I2 = (c); } } while(0)

#define UPDL(v, c, M1, I1, M2, I2) do{ \
    bool lt1_ = (v) < (M1) || ((v) == (M1) && (c) < (I1)); \
    bool lt2_ = (v) < (M2) || ((v) == (M2) && (c) < (I2)); \
    if (lt1_) { M2 = M1; I2 = I1; M1 = (v); I1 = (c); } \
    else if (lt2_) { M2 = (v); I2 = (c); } } while(0)

// ---------- MFMA scan: one wave = 64 points, all 4096 codes ----------
__global__ __launch_bounds__(64) void scan_mfma(const float* __restrict__ x,
                                                const short* __restrict__ cf,
                                                const float* __restrict__ csq,
                                                float4* __restrict__ top2) {
    const int wave = blockIdx.x;          // 0..1023
    const int lane = threadIdx.x;         // 0..63
    const int col  = lane & 15;
    const int grp  = lane >> 4;
    const int pbase = wave * 64;

    // Load 64 points' B-frags, split into bf16 hi/lo in-register.
    // B-frag layout: lane holds B[k=(lane>>4)*8 + j][col=lane&15].
    short8v xh[4][2], xl[4][2];
#pragma unroll
    for (int t = 0; t < 4; ++t) {
#pragma unroll
        for (int h = 0; h < 2; ++h) {
            const float* xp = x + (size_t)(pbase + t * 16 + col) * CODE_DIM + h * 32 + grp * 8;
            float4 v0 = *(const float4*)(xp);
            float4 v1 = *(const float4*)(xp + 4);
            float f[8] = {v0.x, v0.y, v0.z, v0.w, v1.x, v1.y, v1.z, v1.w};
            short8v H, L;
#pragma unroll
            for (int j = 0; j < 8; ++j) {
                unsigned short hb = f2bf(f[j]);
                H[j] = (short)hb;
                L[j] = (short)f2bf(f[j] - bf2f(hb));
            }
            xh[t][h] = H; xl[t][h] = L;
        }
    }

    float m1[4], m2[4];
    int   i1[4], i2[4];
#pragma unroll
    for (int t = 0; t < 4; ++t) { m1[t] = 3e38f; m2[t] = 3e38f; i1[t] = 0; i2[t] = 0; }

#define LOAD_TILE(CT, AF, CQ) do { \
    const short* p_ = cf + ((size_t)(CT) * 4 * 64 + lane) * 8; \
    AF[0] = *(const short8v*)(p_); \
    AF[1] = *(const short8v*)(p_ + 64 * 8); \
    AF[2] = *(const short8v*)(p_ + 2 * 64 * 8); \
    AF[3] = *(const short8v*)(p_ + 3 * 64 * 8); \
    CQ = *(const float4*)(csq + (CT) * 16 + grp * 4); } while(0)

#define COMPUTE_TILE(CT, AF, CQ) do { \
    const int cbase_ = (CT) * 16 + grp * 4; \
    _Pragma("unroll") \
    for (int t = 0; t < 4; ++t) { \
        f32x4 a; a[0] = CQ.x; a[1] = CQ.y; a[2] = CQ.z; a[3] = CQ.w; \
        a = MFMA16(AF[0], xh[t][0], a, 0, 0, 0); \
        a = MFMA16(AF[1], xh[t][1], a, 0, 0, 0); \
        a = MFMA16(AF[0], xl[t][0], a, 0, 0, 0); \
        a = MFMA16(AF[1], xl[t][1], a, 0, 0, 0); \
        a = MFMA16(AF[2], xh[t][0], a, 0, 0, 0); \
        a = MFMA16(AF[3], xh[t][1], a, 0, 0, 0); \
        _Pragma("unroll") \
        for (int r = 0; r < 4; ++r) UPD(a[r], cbase_ + r, m1[t], i1[t], m2[t], i2[t]); \
    } } while(0)

    short8v A0[4], A1[4];
    float4 q0, q1;
    LOAD_TILE(0, A0, q0);
#pragma unroll 4
    for (int it = 0; it < 128; ++it) {
        const int t0 = 2 * it, t1 = 2 * it + 1;
        const int t2 = (t1 + 1 < NTILES) ? t1 + 1 : 0;
        LOAD_TILE(t1, A1, q1);
        COMPUTE_TILE(t0, A0, q0);
        LOAD_TILE(t2, A0, q0);
        COMPUTE_TILE(t1, A1, q1);
    }

    // cross-lane merge: lanes l, l^16, l^32 hold disjoint code subsets of point col
#pragma unroll
    for (int t = 0; t < 4; ++t) {
#pragma unroll
        for (int off = 16; off <= 32; off <<= 1) {
            float om1 = __shfl_xor(m1[t], off);
            int   oi1 = __shfl_xor(i1[t], off);
            float om2 = __shfl_xor(m2[t], off);
            int   oi2 = __shfl_xor(i2[t], off);
            UPDL(om1, oi1, m1[t], i1[t], m2[t], i2[t]);
            UPDL(om2, oi2, m1[t], i1[t], m2[t], i2[t]);
        }
    }
    if (lane < 16) {
#pragma unroll
        for (int t = 0; t < 4; ++t) {
            top2[pbase + t * 16 + lane] =
                make_float4(m1[t], __int_as_float(i1[t]), m2[t], __int_as_float(i2[t]));
        }
    }
#undef LOAD_TILE
#undef COMPUTE_TILE
}

// ---------- final index: f64 refine of the two candidates ----------
__global__ __launch_bounds__(256) void emit1(const float* __restrict__ x,
                                             const float* __restrict__ cb,
                                             const float4* __restrict__ top2,
                                             float* __restrict__ idx_out,
                                             float* __restrict__ bc_acc) {
    const int p = blockIdx.x * 256 + threadIdx.x;
    float4 tp = top2[p];
    int ia = __float_as_int(tp.y);
    int ib = __float_as_int(tp.w);

    const float* xr = x  + (size_t)p  * CODE_DIM;
    const float* c1 = cb + (size_t)ia * CODE_DIM;
    const float* c2 = cb + (size_t)ib * CODE_DIM;
    double dot1 = 0.0, q1 = 0.0, dot2 = 0.0, q2 = 0.0;
#pragma unroll 8
    for (int d = 0; d < CODE_DIM; ++d) {
        double xv = (double)xr[d];
        double a  = (double)c1[d];
        double b  = (double)c2[d];
        dot1 += a * xv; q1 += a * a;
        dot2 += b * xv; q2 += b * b;
    }
    double e1 = q1 - 2.0 * dot1;
    double e2 = q2 - 2.0 * dot2;
    int fin;
    if (e1 < e2)      fin = ia;
    else if (e2 < e1) fin = ib;
    else              fin = (ia < ib) ? ia : ib;

    idx_out[p] = (float)fin;
    atomicAdd(&bc_acc[fin], 1.0f);
}

// ---------- quantized write + embed_sum scatter: one wave per point ----------
__global__ __launch_bounds__(256) void emit2(const float* __restrict__ x,
                                             const float* __restrict__ cb,
                                             const float* __restrict__ idx_out,
                                             float* __restrict__ q_out,
                                             float* __restrict__ es_acc) {
    const int p    = blockIdx.x * 4 + (threadIdx.x >> 6);
    const int lane = threadIdx.x & 63;
    const int fin  = (int)idx_out[p];
    float xv = x[(size_t)p * CODE_DIM + lane];
    float cv = cb[(size_t)fin * CODE_DIM + lane];
    q_out[(size_t)p * CODE_DIM + lane] = cv;
    atomicAdd(&es_acc[(size_t)fin * CODE_DIM + lane], xv);
}

__global__ __launch_bounds__(256) void ncs_kernel(const float* __restrict__ cs_in,
                                                  const float* __restrict__ bc_acc,
                                                  float* __restrict__ cs_out,
                                                  float* __restrict__ n_acc) {
    int k = blockIdx.x * 256 + threadIdx.x;   // 4096 threads
    float v = DECAYF * cs_in[k] + (1.0f - DECAYF) * bc_acc[k];
    cs_out[k] = v;
    float s = v;
#pragma unroll
    for (int off = 32; off > 0; off >>= 1) s += __shfl_down(s, off);
    if ((threadIdx.x & 63) == 0) atomicAdd(n_acc, s);
}

__global__ __launch_bounds__(256) void finalize_kernel(const float* __restrict__ ema_in,
                                                       const float* __restrict__ es_acc,
                                                       const float* __restrict__ cs_out,
                                                       const float* __restrict__ n_acc,
                                                       float* __restrict__ ema_out,
                                                       float* __restrict__ cb_out) {
    int idx = blockIdx.x * 256 + threadIdx.x;   // 262144 threads
    int k   = idx >> 6;
    float n = *n_acc;
    float ncs = cs_out[k];
    float smoothed = (ncs + EPSF) / (n + (float)NUM_CODES * EPSF) * n;
    float ew = DECAYF * ema_in[idx] + (1.0f - DECAYF) * es_acc[idx];
    ema_out[idx] = ew;
    cb_out[idx]  = ew / smoothed;
}

extern "C" void kernel_launch(void* const* d_in, const int* in_sizes, int n_in,
                              void* d_out, int out_size, void* d_ws, size_t ws_size,
                              hipStream_t stream) {
    const float* x    = (const float*)d_in[0];
    const float* cb   = (const float*)d_in[1];
    const float* cs   = (const float*)d_in[2];
    const float* emaw = (const float*)d_in[3];
    float* out = (float*)d_out;
    float* ws  = (float*)d_ws;

    hipMemsetAsync(ws, 0, (size_t)(WS_N + 1) * sizeof(float), stream);

    csq_kernel<<<NUM_CODES / 256, 256, 0, stream>>>(cb, ws + WS_CSQ);
    prep_cf<<<128, 256, 0, stream>>>(cb, (short*)(ws + WS_CF));

    scan_mfma<<<NPTS / 64, 64, 0, stream>>>(
        x, (const short*)(ws + WS_CF), ws + WS_CSQ, (float4*)(ws + WS_TOP2));

    emit1<<<NPTS / 256, 256, 0, stream>>>(
        x, cb, (const float4*)(ws + WS_TOP2), out + OUT_IDX, ws + WS_BC);

    emit2<<<NPTS / 4, 256, 0, stream>>>(
        x, cb, out + OUT_IDX, out + OUT_Q, ws + WS_ES);

    ncs_kernel<<<NUM_CODES / 256, 256, 0, stream>>>(
        cs, ws + WS_BC, out + OUT_CS, ws + WS_N);

    finalize_kernel<<<(NUM_CODES * CODE_DIM) / 256, 256, 0, stream>>>(
        emaw, ws + WS_ES, out + OUT_CS, ws + WS_N, out + OUT_EMA, out + OUT_CB);
}

// Round 3
// 321.998 us; speedup vs baseline: 4.5450x; 1.7640x over previous
//
#include <hip/hip_runtime.h>

#define NUM_CODES 4096
#define CODE_DIM  64
#define NPTS      65536              // B*S = 16*4096
#define NTILES    (NUM_CODES / 16)   // 256 code tiles
#define NSEG2     4                  // code segments in scan (occupancy)
#define SEGTILES  (NTILES / NSEG2)   // 64 tiles per segment
#define DECAYF    0.99f
#define EPSF      1e-5f
#define THRF      0.02f              // certify threshold (MFMA err bound ~1.5e-3)

typedef __attribute__((ext_vector_type(8))) short short8v;
typedef __attribute__((ext_vector_type(4))) float f32x4;
#define MFMA16 __builtin_amdgcn_mfma_f32_16x16x32_bf16

// ---------------- workspace layout (float indices) ----------------
#define WS_BC   0                    // 4096   batch_cluster acc
#define WS_ES   4096                 // 262144 embed_sum acc
#define WS_N    266240               // 1      n acc (float)
#define WS_CNT  266241               // 1      flagged count (int)
#define WS_CSQ  266244               // 4096   codebook sq-norms (16B aligned)
#define WS_CF   270340               // 262144 floats = A-frag codebook (bf16 hi/lo)
#define WS_TOP2 532484               // 65536*4 segs * float4 {m1, i1, m2, pad}
// flagged list overlays WS_CF (dead after scan): 65536 ints fit in 262144 floats

// ---------------- output layout ----------------
#define OUT_Q    0
#define OUT_IDX  4194304
#define OUT_CB   4259840
#define OUT_CS   4521984
#define OUT_EMA  4526080

__device__ __forceinline__ unsigned short f2bf(float f) {
    unsigned u = __float_as_uint(f);
    u += 0x7FFFu + ((u >> 16) & 1u);
    return (unsigned short)(u >> 16);
}
__device__ __forceinline__ float bf2f(unsigned short h) {
    return __uint_as_float(((unsigned)h) << 16);
}

// ---------- codebook squared norms ----------
__global__ __launch_bounds__(256) void csq_kernel(const float* __restrict__ cb,
                                                  float* __restrict__ csq) {
    int k = blockIdx.x * 256 + threadIdx.x;   // 4096 threads
    const float4* cp = (const float4*)(cb + (size_t)k * CODE_DIM);
    float s0 = 0.f, s1 = 0.f, s2 = 0.f, s3 = 0.f;
#pragma unroll
    for (int j = 0; j < 16; ++j) {
        float4 v = cp[j];
        s0 = fmaf(v.x, v.x, s0);
        s1 = fmaf(v.y, v.y, s1);
        s2 = fmaf(v.z, v.z, s2);
        s3 = fmaf(v.w, v.w, s3);
    }
    csq[k] = (s0 + s1) + (s2 + s3);
}

// ---------- codebook -> bf16 hi/lo A-fragment layout ----------
// cf[ctile][frag][lane][8 shorts], frag: 0=hi k0, 1=hi k1, 2=lo k0, 3=lo k1.
// A-frag (16x16x32): lane holds A[row=lane&15][k=(lane>>4)*8 + j].
__global__ __launch_bounds__(256) void prep_cf(const float* __restrict__ cb,
                                               short* __restrict__ cf) {
    int t = blockIdx.x * 256 + threadIdx.x;   // 32768 threads
    int ctile = t >> 7;
    int rem   = t & 127;
    int khalf = rem >> 6;
    int lane  = rem & 63;
    int code  = ctile * 16 + (lane & 15);
    int kbase = khalf * 32 + (lane >> 4) * 8;
    const float* src = cb + (size_t)code * CODE_DIM + kbase;
    short8v H, L;
#pragma unroll
    for (int j = 0; j < 8; ++j) {
        float s = -2.0f * src[j];
        unsigned short h = f2bf(s);
        H[j] = (short)h;
        L[j] = (short)f2bf(s - bf2f(h));
    }
    *(short8v*)(cf + ((size_t)(ctile * 4 + khalf) * 64 + lane) * 8)     = H;
    *(short8v*)(cf + ((size_t)(ctile * 4 + 2 + khalf) * 64 + lane) * 8) = L;
}

// ---------- MFMA scan: one wave = 64 points x one code segment ----------
// Fold: exact-f32 top-2 values via min/med3 + index of m1 only (4 VALU/elem).
__global__ __launch_bounds__(64) void scan_mfma(const float* __restrict__ x,
                                                const short* __restrict__ cf,
                                                const float* __restrict__ csq,
                                                float4* __restrict__ top2) {
    const int wave = blockIdx.x;          // 0..4095
    const int seg  = wave & (NSEG2 - 1);
    const int pw   = wave >> 2;
    const int lane = threadIdx.x;
    const int col  = lane & 15;
    const int grp  = lane >> 4;
    const int pbase = pw * 64;

    // B-frags for 64 points, bf16 hi/lo split in-register.
    // B-frag (16x16x32): lane holds B[k=(lane>>4)*8 + j][col=lane&15].
    short8v xh[4][2], xl[4][2];
#pragma unroll
    for (int t = 0; t < 4; ++t) {
#pragma unroll
        for (int h = 0; h < 2; ++h) {
            const float* xp = x + (size_t)(pbase + t * 16 + col) * CODE_DIM + h * 32 + grp * 8;
            float4 v0 = *(const float4*)(xp);
            float4 v1 = *(const float4*)(xp + 4);
            float f[8] = {v0.x, v0.y, v0.z, v0.w, v1.x, v1.y, v1.z, v1.w};
            short8v H, L;
#pragma unroll
            for (int j = 0; j < 8; ++j) {
                unsigned short hb = f2bf(f[j]);
                H[j] = (short)hb;
                L[j] = (short)f2bf(f[j] - bf2f(hb));
            }
            xh[t][h] = H; xl[t][h] = L;
        }
    }

    float m1[4], m2[4];
    int   i1[4];
#pragma unroll
    for (int t = 0; t < 4; ++t) { m1[t] = 3e38f; m2[t] = 3e38f; i1[t] = 0; }

#define LOAD_TILE(CT, AF, CQ) do { \
    const short* p_ = cf + ((size_t)(CT) * 4 * 64 + lane) * 8; \
    AF[0] = *(const short8v*)(p_); \
    AF[1] = *(const short8v*)(p_ + 64 * 8); \
    AF[2] = *(const short8v*)(p_ + 2 * 64 * 8); \
    AF[3] = *(const short8v*)(p_ + 3 * 64 * 8); \
    CQ = *(const float4*)(csq + (CT) * 16 + grp * 4); } while(0)

#define COMPUTE_TILE(CT, AF, CQ) do { \
    const int cbase_ = (CT) * 16 + grp * 4; \
    _Pragma("unroll") \
    for (int t = 0; t < 4; ++t) { \
        f32x4 a; a[0] = CQ.x; a[1] = CQ.y; a[2] = CQ.z; a[3] = CQ.w; \
        a = MFMA16(AF[0], xh[t][0], a, 0, 0, 0); \
        a = MFMA16(AF[1], xh[t][1], a, 0, 0, 0); \
        a = MFMA16(AF[0], xl[t][0], a, 0, 0, 0); \
        a = MFMA16(AF[1], xl[t][1], a, 0, 0, 0); \
        a = MFMA16(AF[2], xh[t][0], a, 0, 0, 0); \
        a = MFMA16(AF[3], xh[t][1], a, 0, 0, 0); \
        _Pragma("unroll") \
        for (int r = 0; r < 4; ++r) { \
            float k_ = a[r]; \
            bool lt_ = k_ < m1[t]; \
            float nm2_ = __builtin_amdgcn_fmed3f(m1[t], m2[t], k_); \
            i1[t] = lt_ ? (cbase_ + r) : i1[t]; \
            m1[t] = fminf(m1[t], k_); \
            m2[t] = nm2_; \
        } \
    } } while(0)

    short8v A0[4], A1[4];
    float4 q0, q1;
    const int tb = seg * SEGTILES;
    LOAD_TILE(tb, A0, q0);
#pragma unroll 4
    for (int it = 0; it < SEGTILES / 2; ++it) {
        const int t0 = tb + 2 * it, t1 = t0 + 1;
        const int t2 = (2 * it + 2 < SEGTILES) ? t1 + 1 : tb;
        LOAD_TILE(t1, A1, q1);
        COMPUTE_TILE(t0, A0, q0);
        LOAD_TILE(t2, A0, q0);
        COMPUTE_TILE(t1, A1, q1);
    }
#undef LOAD_TILE
#undef COMPUTE_TILE

    // cross-lane merge: lanes l, l^16, l^32 hold disjoint code subsets of point col
#pragma unroll
    for (int t = 0; t < 4; ++t) {
#pragma unroll
        for (int off = 16; off <= 32; off <<= 1) {
            float om1 = __shfl_xor(m1[t], off);
            int   oi1 = __shfl_xor(i1[t], off);
            float om2 = __shfl_xor(m2[t], off);
            float nm2 = fminf(fmaxf(m1[t], om1), fminf(m2[t], om2));
            bool take = (om1 < m1[t]) || (om1 == m1[t] && oi1 < i1[t]);
            i1[t] = take ? oi1 : i1[t];
            m1[t] = fminf(m1[t], om1);
            m2[t] = nm2;
        }
    }
    if (lane < 16) {
#pragma unroll
        for (int t = 0; t < 4; ++t) {
            top2[(size_t)(pbase + t * 16 + lane) * NSEG2 + seg] =
                make_float4(m1[t], __int_as_float(i1[t]), m2[t], 0.0f);
        }
    }
}

// ---------- merge segments; certify or flag for exact fallback ----------
__global__ __launch_bounds__(256) void emit1(const float4* __restrict__ top2,
                                             float* __restrict__ idx_out,
                                             float* __restrict__ bc_acc,
                                             int* __restrict__ flagged,
                                             int* __restrict__ cnt) {
    const int p = blockIdx.x * 256 + threadIdx.x;
    const float4* tp = top2 + (size_t)p * NSEG2;
    float4 t0 = tp[0];
    float m1 = t0.x; int i1 = __float_as_int(t0.y); float m2 = t0.z;
#pragma unroll
    for (int s = 1; s < NSEG2; ++s) {
        float4 t = tp[s];
        float om1 = t.x; int oi1 = __float_as_int(t.y); float om2 = t.z;
        float nm2 = fminf(fmaxf(m1, om1), fminf(m2, om2));
        bool take = (om1 < m1) || (om1 == m1 && oi1 < i1);
        if (take) i1 = oi1;
        m1 = fminf(m1, om1);
        m2 = nm2;
    }
    if (m2 - m1 >= THRF) {
        idx_out[p] = (float)i1;
        atomicAdd(&bc_acc[i1], 1.0f);
    } else {
        int pos = atomicAdd(cnt, 1);
        flagged[pos] = p;
    }
}

// ---------- exact f64 full rescan for uncertified points (wave per point) ----------
__global__ __launch_bounds__(64) void fallback_kernel(const float* __restrict__ x,
                                                      const float* __restrict__ cb,
                                                      const int* __restrict__ flagged,
                                                      const int* __restrict__ cnt,
                                                      float* __restrict__ idx_out,
                                                      float* __restrict__ bc_acc) {
    __shared__ float xs[CODE_DIM];
    const int lane = threadIdx.x;
    const int n = *cnt;
    for (int w = blockIdx.x; w < n; w += 1024) {
        const int p = flagged[w];
        xs[lane] = x[(size_t)p * CODE_DIM + lane];
        __syncthreads();
        double best = 1e300; int bi = 0;
        for (int j = 0; j < 64; ++j) {
            const int c = lane + 64 * j;   // ascending per lane
            const float4* cp = (const float4*)(cb + (size_t)c * CODE_DIM);
            double acc = 0.0;
#pragma unroll
            for (int q = 0; q < 16; ++q) {
                float4 cv = cp[q];
                const float4 xv = *(const float4*)(xs + q * 4);
                double d0 = (double)xv.x - (double)cv.x;
                double d1 = (double)xv.y - (double)cv.y;
                double d2 = (double)xv.z - (double)cv.z;
                double d3 = (double)xv.w - (double)cv.w;
                acc = fma(d0, d0, acc);
                acc = fma(d1, d1, acc);
                acc = fma(d2, d2, acc);
                acc = fma(d3, d3, acc);
            }
            if (acc < best) { best = acc; bi = c; }
        }
#pragma unroll
        for (int off = 1; off < 64; off <<= 1) {
            double ob = __shfl_xor(best, off);
            int   obi = __shfl_xor(bi, off);
            if (ob < best || (ob == best && obi < bi)) { best = ob; bi = obi; }
        }
        if (lane == 0) {
            idx_out[p] = (float)bi;
            atomicAdd(&bc_acc[bi], 1.0f);
        }
        __syncthreads();
    }
}

// ---------- quantized write + embed_sum scatter: one wave per point ----------
__global__ __launch_bounds__(256) void emit2(const float* __restrict__ x,
                                             const float* __restrict__ cb,
                                             const float* __restrict__ idx_out,
                                             float* __restrict__ q_out,
                                             float* __restrict__ es_acc) {
    const int p    = blockIdx.x * 4 + (threadIdx.x >> 6);
    const int lane = threadIdx.x & 63;
    const int fin  = (int)idx_out[p];
    float xv = x[(size_t)p * CODE_DIM + lane];
    float cv = cb[(size_t)fin * CODE_DIM + lane];
    q_out[(size_t)p * CODE_DIM + lane] = cv;
    atomicAdd(&es_acc[(size_t)fin * CODE_DIM + lane], xv);
}

__global__ __launch_bounds__(256) void ncs_kernel(const float* __restrict__ cs_in,
                                                  const float* __restrict__ bc_acc,
                                                  float* __restrict__ cs_out,
                                                  float* __restrict__ n_acc) {
    int k = blockIdx.x * 256 + threadIdx.x;   // 4096 threads
    float v = DECAYF * cs_in[k] + (1.0f - DECAYF) * bc_acc[k];
    cs_out[k] = v;
    float s = v;
#pragma unroll
    for (int off = 32; off > 0; off >>= 1) s += __shfl_down(s, off);
    if ((threadIdx.x & 63) == 0) atomicAdd(n_acc, s);
}

__global__ __launch_bounds__(256) void finalize_kernel(const float* __restrict__ ema_in,
                                                       const float* __restrict__ es_acc,
                                                       const float* __restrict__ cs_out,
                                                       const float* __restrict__ n_acc,
                                                       float* __restrict__ ema_out,
                                                       float* __restrict__ cb_out) {
    int idx = blockIdx.x * 256 + threadIdx.x;   // 262144 threads
    int k   = idx >> 6;
    float n = *n_acc;
    float ncs = cs_out[k];
    float smoothed = (ncs + EPSF) / (n + (float)NUM_CODES * EPSF) * n;
    float ew = DECAYF * ema_in[idx] + (1.0f - DECAYF) * es_acc[idx];
    ema_out[idx] = ew;
    cb_out[idx]  = ew / smoothed;
}

extern "C" void kernel_launch(void* const* d_in, const int* in_sizes, int n_in,
                              void* d_out, int out_size, void* d_ws, size_t ws_size,
                              hipStream_t stream) {
    const float* x    = (const float*)d_in[0];
    const float* cb   = (const float*)d_in[1];
    const float* cs   = (const float*)d_in[2];
    const float* emaw = (const float*)d_in[3];
    float* out = (float*)d_out;
    float* ws  = (float*)d_ws;

    // zero bc + es + n + cnt (contiguous)
    hipMemsetAsync(ws, 0, (size_t)(WS_CNT + 1) * sizeof(float), stream);

    csq_kernel<<<NUM_CODES / 256, 256, 0, stream>>>(cb, ws + WS_CSQ);
    prep_cf<<<128, 256, 0, stream>>>(cb, (short*)(ws + WS_CF));

    scan_mfma<<<(NPTS / 64) * NSEG2, 64, 0, stream>>>(
        x, (const short*)(ws + WS_CF), ws + WS_CSQ, (float4*)(ws + WS_TOP2));

    emit1<<<NPTS / 256, 256, 0, stream>>>(
        (const float4*)(ws + WS_TOP2), out + OUT_IDX, ws + WS_BC,
        (int*)(ws + WS_CF), (int*)(ws + WS_CNT));

    fallback_kernel<<<1024, 64, 0, stream>>>(
        x, cb, (const int*)(ws + WS_CF), (const int*)(ws + WS_CNT),
        out + OUT_IDX, ws + WS_BC);

    emit2<<<NPTS / 4, 256, 0, stream>>>(
        x, cb, out + OUT_IDX, out + OUT_Q, ws + WS_ES);

    ncs_kernel<<<NUM_CODES / 256, 256, 0, stream>>>(
        cs, ws + WS_BC, out + OUT_CS, ws + WS_N);

    finalize_kernel<<<(NUM_CODES * CODE_DIM) / 256, 256, 0, stream>>>(
        emaw, ws + WS_ES, out + OUT_CS, ws + WS_N, out + OUT_EMA, out + OUT_CB);
}